// Round 5
// baseline (162.567 us; speedup 1.0000x reference)
//
#include <hip/hip_runtime.h>

#define EPSN 1e-12f

// ---- problem constants ----
#define NB   4
#define CC   128
#define KK_  64
#define HH   40
#define WW   40
#define HWP  1600      // H*W
#define HO   18
#define WO   18
#define HWO  324       // HO*WO
#define KCC  8192      // K*C

// ws layout (floats)
#define WS_T   0                      // 4*324*8192 = 10,616,832
#define WS_XN  10616832               // 4*1600*128 = 819200
#define WS_A   11436032               // 4*1600*64  = 409600
#define WS_GP  11845632               // 64*8192    = 524288
#define WS_G0  12369920               // 64*64      = 4096

// =====================================================================
// Kernel 1: per-pixel L2 norm -> xn (pix-major), conv dots + softmax -> a
// grid 100 x 1024 threads. 64 pixels per block. All global loads coalesced
// via LDS transpose.
// =====================================================================
__global__ __launch_bounds__(1024) void k1_norm_assign(
    const float* __restrict__ x, const float* __restrict__ w,
    float* __restrict__ xn, float* __restrict__ aout)
{
  __shared__ float xs[64][133];
  __shared__ float ds[64][65];
  __shared__ float invs[64];
  const int t = threadIdx.x;
  const int b = blockIdx.x;          // 0..99
  const int n = b / 25;
  const int pixb = (b % 25) * 64;
  const float* xb = x + (size_t)n * CC * HWP + pixb;

  // ---- Phase A: coalesced load + LDS transpose
  {
    const int pix = t & 63, cs = t >> 6;   // cs 0..15
    #pragma unroll
    for (int j = 0; j < 8; ++j) {
      const int c = cs + 16 * j;
      xs[pix][c] = xb[c * HWP + pix];      // 256B coalesced per instr
    }
  }
  __syncthreads();
  // ---- per-pixel sumsq -> inv norm
  {
    const int p = t >> 4, q = t & 15;
    float ss = 0.f;
    #pragma unroll
    for (int j = 0; j < 8; ++j) { float v = xs[p][q + 16 * j]; ss += v * v; }
    ss += __shfl_xor(ss, 1); ss += __shfl_xor(ss, 2);
    ss += __shfl_xor(ss, 4); ss += __shfl_xor(ss, 8);
    if (q == 0) invs[p] = 1.f / fmaxf(sqrtf(ss), EPSN);
  }
  __syncthreads();
  // ---- rescale in LDS + coalesced xn write
  {
    float* xno = xn + ((size_t)n * HWP + pixb) * CC;
    #pragma unroll
    for (int rr = 0; rr < 8; ++rr) {
      const int i = t + rr * 1024;
      const int pp = i >> 7, c = i & 127;
      const float v = xs[pp][c] * invs[pp];
      xs[pp][c] = v;
      xno[i] = v;
    }
  }
  __syncthreads();
  // ---- Phase B: dots. wave wv -> k = wv*4..wv*4+3 (wave-uniform w), lane=pixel
  {
    const int lane = t & 63;
    const int wv = __builtin_amdgcn_readfirstlane(t >> 6);   // 0..15
    float acc[4] = {0.f, 0.f, 0.f, 0.f};
    for (int c = 0; c < CC; ++c) {
      const float vn = xs[lane][c];
      #pragma unroll
      for (int kk = 0; kk < 4; ++kk)
        acc[kk] += vn * w[(wv * 4 + kk) * CC + c];
    }
    #pragma unroll
    for (int kk = 0; kk < 4; ++kk) ds[lane][wv * 4 + kk] = acc[kk];
  }
  __syncthreads();
  // ---- Phase C: softmax per pixel. thread (p = t>>4, q = t&15), k = q+16kk
  {
    const int p = t >> 4, q = t & 15;
    float v[4]; float m = -3.4e38f;
    #pragma unroll
    for (int kk = 0; kk < 4; ++kk){ v[kk] = ds[p][q + 16 * kk]; m = fmaxf(m, v[kk]); }
    m = fmaxf(m, __shfl_xor(m, 1)); m = fmaxf(m, __shfl_xor(m, 2));
    m = fmaxf(m, __shfl_xor(m, 4)); m = fmaxf(m, __shfl_xor(m, 8));
    float s = 0.f;
    #pragma unroll
    for (int kk = 0; kk < 4; ++kk){ v[kk] = __expf(v[kk] - m); s += v[kk]; }
    s += __shfl_xor(s, 1); s += __shfl_xor(s, 2);
    s += __shfl_xor(s, 4); s += __shfl_xor(s, 8);
    const float is = 1.f / s;
    #pragma unroll
    for (int kk = 0; kk < 4; ++kk) ds[p][q + 16 * kk] = v[kk] * is;
  }
  __syncthreads();
  {
    float* ao = aout + ((size_t)n * HWP + pixb) * KK_;
    #pragma unroll
    for (int rr = 0; rr < 4; ++rr) {
      const int i = t + rr * 1024;
      ao[i] = ds[i >> 6][i & 63];
    }
  }
}

// =====================================================================
// rank-25 outer-product accumulate. Lane mapping (store-coalescing):
// lane = (h = lane>>5, l5 = lane&31); lane owns k(m) = kbase + 2m + h
// (m = 0..7) and c = l5*4 .. l5*4+3. Wave's 2048 outputs are CONTIGUOUS
// in kc: kc = kbase*128 + m*256 + lane*4 + d.
// xs read: contiguous 16B/lane b128 (conflict-free, h-broadcast).
// a read: 2-address broadcast b32 (adjacent banks, conflict-free).
// =====================================================================
__device__ __forceinline__ void dots25(const float (*a_s)[64], const float (*xs)[128],
                                       int kbase, int h, int c0,
                                       float acc[32], float s0[8])
{
  #pragma unroll
  for (int p = 0; p < 25; ++p) {
    const float4 x4 = *(const float4*)&xs[p][c0];
    #pragma unroll
    for (int m = 0; m < 8; ++m) {
      const float av = a_s[p][kbase + 2 * m + h];
      s0[m] += av;
      acc[m * 4 + 0] += av * x4.x;
      acc[m * 4 + 1] += av * x4.y;
      acc[m * 4 + 2] += av * x4.z;
      acc[m * 4 + 3] += av * x4.w;
    }
  }
}

// =====================================================================
// Kernel 2: 1296 regional-window blocks (write final vlad into T[n][r][kc],
// fully coalesced) + 64 blocks of vlad_full partials. 256 threads (4 waves);
// wave wv owns k = wv*16 .. wv*16+15.
// =====================================================================
__global__ __launch_bounds__(256) void k2_main(
    const float* __restrict__ xn, const float* __restrict__ aw,
    const float* __restrict__ cent, float* __restrict__ T,
    float* __restrict__ Gpart, float* __restrict__ G0part)
{
  __shared__ __align__(16) float a_s[25][64];
  __shared__ __align__(16) float xs[25][128];
  __shared__ float red[4];
  const int t = threadIdx.x;
  const int lane = t & 63;
  const int wv = t >> 6;            // 0..3
  const int h = lane >> 5;          // 0..1
  const int l5 = lane & 31;
  const int c0 = l5 << 2;
  const int kbase = wv * 16;
  // XCD-chunked bijective swizzle (1360 % 8 == 0): L2 read locality.
  const int bid = (blockIdx.x & 7) * 170 + (blockIdx.x >> 3);

  float acc[32];
  #pragma unroll
  for (int j = 0; j < 32; ++j) acc[j] = 0.f;
  float s0[8];
  #pragma unroll
  for (int m = 0; m < 8; ++m) s0[m] = 0.f;

  if (bid < 1296) {
    // ---------------- regional window ----------------
    const int n = bid / HWO, r = bid % HWO, ho = r / WO, wo = r % WO;
    for (int it = wv; it < 25; it += 4) {
      const int pix = (2 * ho + it / 5) * WW + 2 * wo + (it % 5);
      a_s[it][lane] = aw[((size_t)n * HWP + pix) * KK_ + lane];
      const float* xp = xn + ((size_t)n * HWP + pix) * CC;
      xs[it][lane]      = xp[lane];
      xs[it][lane + 64] = xp[lane + 64];
    }
    __syncthreads();

    dots25(a_s, xs, kbase, h, c0, acc, s0);

    // epilogue: centroid correction, /25, intra-norm (C), global norm (K*C)
    float ssm[8], rnm[8];
    #pragma unroll
    for (int m = 0; m < 8; ++m) {
      const int k = kbase + 2 * m + h;
      const float4 c4 = *(const float4*)&cent[(size_t)k * CC + c0];
      const float cv[4] = {c4.x, c4.y, c4.z, c4.w};
      float ss = 0.f;
      #pragma unroll
      for (int d = 0; d < 4; ++d) {
        const float pv = (acc[m * 4 + d] - cv[d] * s0[m]) * 0.04f;
        acc[m * 4 + d] = pv;
        ss += pv * pv;
      }
      ssm[m] = ss;
    }
    // reduce per-k sumsq over the 32 c-lanes (l5)
    #pragma unroll
    for (int off = 1; off <= 16; off <<= 1) {
      #pragma unroll
      for (int m = 0; m < 8; ++m) ssm[m] += __shfl_xor(ssm[m], off);
    }
    float gpl = 0.f;
    #pragma unroll
    for (int m = 0; m < 8; ++m) {
      rnm[m] = 1.f / fmaxf(sqrtf(ssm[m]), EPSN);
      gpl += ssm[m] * rnm[m] * rnm[m];
    }
    gpl += __shfl_xor(gpl, 32);       // both h-halves -> wave's 16 k's
    if (lane == 0) red[wv] = gpl;
    __syncthreads();
    const float gtot = red[0] + red[1] + red[2] + red[3];
    const float gi = 1.f / fmaxf(sqrtf(gtot), EPSN);

    // fully-coalesced store: 8 x 1KB per wave into T[n][r][kc]
    float* tb = T + ((size_t)n * HWO + r) * KCC + kbase * CC;
    #pragma unroll
    for (int m = 0; m < 8; ++m) {
      const float sc = rnm[m] * gi;
      float4 v;
      v.x = acc[m * 4 + 0] * sc; v.y = acc[m * 4 + 1] * sc;
      v.z = acc[m * 4 + 2] * sc; v.w = acc[m * 4 + 3] * sc;
      *(float4*)&tb[m * 256 + lane * 4] = v;
    }
  } else {
    // ---------------- vlad_full partials: 100-pixel chunk, 4 rounds ------
    const int pid = bid - 1296;            // 0..63
    const int n = pid >> 4, ch = pid & 15;
    const int pixb = n * HWP + ch * 100;   // global pixel index
    #pragma unroll 1
    for (int rr = 0; rr < 4; ++rr) {
      for (int it = wv; it < 25; it += 4) {
        const int pg = pixb + rr * 25 + it;
        a_s[it][lane] = aw[(size_t)pg * KK_ + lane];
        const float* xp = xn + (size_t)pg * CC;
        xs[it][lane]      = xp[lane];
        xs[it][lane + 64] = xp[lane + 64];
      }
      __syncthreads();
      dots25(a_s, xs, kbase, h, c0, acc, s0);
      __syncthreads();
    }
    if (l5 == 0) {
      #pragma unroll
      for (int m = 0; m < 8; ++m)
        G0part[(size_t)pid * KK_ + kbase + 2 * m + h] = s0[m];
    }
    float* gb = Gpart + (size_t)pid * KCC + kbase * CC;
    #pragma unroll
    for (int m = 0; m < 8; ++m) {
      float4 v;
      v.x = acc[m * 4 + 0]; v.y = acc[m * 4 + 1];
      v.z = acc[m * 4 + 2]; v.w = acc[m * 4 + 3];
      *(float4*)&gb[m * 256 + lane * 4] = v;
    }
  }
}

// =====================================================================
// Kernel 4: transpose T[n][r][kc] -> out[n][kc][r]. Coalesced both sides.
// grid = 4n x 128 kc-tiles(64) x 3 r-chunks(112,112,100). 256 threads.
// =====================================================================
__global__ __launch_bounds__(256) void k4_transpose(
    const float* __restrict__ T, float* __restrict__ out)
{
  __shared__ float tile[112][65];
  const int t = threadIdx.x;
  const int b = blockIdx.x;            // 0..1535
  const int n = b / 384;
  const int rem = b % 384;
  const int kcT = rem / 3, rT = rem % 3;
  const int kc0 = kcT * 64;
  const int r0 = rT * 112;
  const int rows = (rT == 2) ? 100 : 112;
  const int w = t >> 6, lane = t & 63;

  for (int rr = w; rr < rows; rr += 4)
    tile[rr][lane] = T[((size_t)n * HWO + r0 + rr) * KCC + kc0 + lane];
  __syncthreads();

  #pragma unroll
  for (int j = 0; j < 16; ++j) {
    const int kcl = w + 4 * j;          // 0..63, wave-uniform
    float* orow = out + (size_t)n * KCC * HWO + (size_t)(kc0 + kcl) * HWO + r0;
    orow[lane] = tile[lane][kcl];
    if (lane + 64 < rows) orow[64 + lane] = tile[64 + lane][kcl];
  }
}

// =====================================================================
// Kernel 3: finalize vlad_full. 4 blocks (one per n) x 1024 threads.
// thread: k = t>>4, 8 c's (c0 = (t&15)*8). Reads 2 MB coalesced.
// =====================================================================
__global__ __launch_bounds__(1024) void k3_full(
    const float* __restrict__ Gpart, const float* __restrict__ G0part,
    const float* __restrict__ cent, float* __restrict__ outF)
{
  __shared__ float red[16];
  const int n = blockIdx.x;
  const int t = threadIdx.x;
  const int k = t >> 4, cg16 = t & 15;
  const int c0 = cg16 * 8;

  float acc[8];
  #pragma unroll
  for (int j = 0; j < 8; ++j) acc[j] = 0.f;
  float g0 = 0.f;
  #pragma unroll 1
  for (int ch = 0; ch < 16; ++ch) {
    const float* gp = Gpart + ((size_t)(n * 16 + ch)) * KCC + (size_t)k * CC + c0;
    const float4 a4 = *(const float4*)(gp);
    const float4 b4 = *(const float4*)(gp + 4);
    acc[0] += a4.x; acc[1] += a4.y; acc[2] += a4.z; acc[3] += a4.w;
    acc[4] += b4.x; acc[5] += b4.y; acc[6] += b4.z; acc[7] += b4.w;
    g0 += G0part[(size_t)(n * 16 + ch) * KK_ + k];
  }

  float ss = 0.f;
  #pragma unroll
  for (int j = 0; j < 8; ++j) {
    const float v = acc[j] - cent[(size_t)k * CC + c0 + j] * g0;
    acc[j] = v;
    ss += v * v;
  }
  ss += __shfl_xor(ss, 1); ss += __shfl_xor(ss, 2);
  ss += __shfl_xor(ss, 4); ss += __shfl_xor(ss, 8);   // over cg16 -> per-k sumsq
  const float rn = 1.f / fmaxf(sqrtf(ss), EPSN);
  float part = (cg16 == 0) ? ss * rn * rn : 0.f;
  #pragma unroll
  for (int o = 1; o < 64; o <<= 1) part += __shfl_xor(part, o);
  if ((t & 63) == 0) red[t >> 6] = part;
  __syncthreads();
  float tot = 0.f;
  #pragma unroll
  for (int i = 0; i < 16; ++i) tot += red[i];
  const float scale = rn * (1.f / fmaxf(sqrtf(tot), EPSN));
  #pragma unroll
  for (int j = 0; j < 8; ++j)
    outF[(size_t)n * KCC + (size_t)k * CC + c0 + j] = acc[j] * scale;
}

// =====================================================================
extern "C" void kernel_launch(void* const* d_in, const int* in_sizes, int n_in,
                              void* d_out, int out_size, void* d_ws, size_t ws_size,
                              hipStream_t stream)
{
  const float* x    = (const float*)d_in[0];
  const float* w    = (const float*)d_in[1];
  const float* cent = (const float*)d_in[2];
  float* out = (float*)d_out;
  float* ws  = (float*)d_ws;

  float* T  = ws + WS_T;
  float* xn = ws + WS_XN;
  float* aw = ws + WS_A;
  float* gp = ws + WS_GP;
  float* g0 = ws + WS_G0;

  k1_norm_assign<<<dim3(100), dim3(1024), 0, stream>>>(x, w, xn, aw);
  k2_main<<<dim3(1360), dim3(256), 0, stream>>>(xn, aw, cent, T, gp, g0);
  k4_transpose<<<dim3(1536), dim3(256), 0, stream>>>(T, out);
  k3_full<<<dim3(NB), dim3(1024), 0, stream>>>(gp, g0, cent,
                                               out + (size_t)NB * KCC * HWO);
}

// Round 6
// 134.770 us; speedup vs baseline: 1.2063x; 1.2063x over previous
//
#include <hip/hip_runtime.h>

#define EPSN 1e-12f

// ---- problem constants ----
#define NB   4
#define CC   128
#define KK_  64
#define HH   40
#define WW   40
#define HWP  1600      // H*W
#define HO   18
#define WO   18
#define HWO  324       // HO*WO
#define KCC  8192      // K*C

// ws layout (floats)
#define WS_T   0                      // 4*324*8192 = 10,616,832
#define WS_XN  10616832               // 4*1600*128 = 819200
#define WS_A   11436032               // 4*1600*64  = 409600
#define WS_GP  11845632               // 64*8192    = 524288
#define WS_G0  12369920               // 64*64      = 4096

// k1 xs swizzle: XOR c-bits[2:6] with px (involution). Write (fixed c, px
// lane-varying) and read (fixed c0, px lane-varying, b128) both spread over
// all 32 banks; 4-float contiguity + 16B alignment preserved.
static __device__ __forceinline__ int swzk1(int c, int px){ return c ^ ((px & 31) << 2); }

// =====================================================================
// Kernel 1: per-pixel L2 norm -> xn (pix-major), conv dots + softmax -> a
// grid 100 x 1024 threads. 64 pixels per block. Coalesced global loads via
// LDS transpose; phase-B LDS reads are b128 (4c) on the swizzled layout.
// =====================================================================
__global__ __launch_bounds__(1024) void k1_norm_assign(
    const float* __restrict__ x, const float* __restrict__ w,
    float* __restrict__ xn, float* __restrict__ aout)
{
  __shared__ __align__(16) float xs[64][128];
  __shared__ float ds[64][65];
  __shared__ float invs[64];
  const int t = threadIdx.x;
  const int b = blockIdx.x;          // 0..99
  const int n = b / 25;
  const int pixb = (b % 25) * 64;
  const float* xb = x + (size_t)n * CC * HWP + pixb;

  // ---- Phase A: coalesced load + swizzled LDS transpose
  {
    const int px = t & 63, cs = t >> 6;   // cs 0..15 (wave-uniform)
    #pragma unroll
    for (int j = 0; j < 8; ++j) {
      const int c = cs + 16 * j;
      xs[px][swzk1(c, px)] = xb[c * HWP + px];   // 256B coalesced per instr
    }
  }
  __syncthreads();
  // ---- per-pixel sumsq -> inv norm. thread (p = t>>4, q = t&15)
  {
    const int p = t >> 4, q = t & 15;
    float ss = 0.f;
    #pragma unroll
    for (int j = 0; j < 8; ++j) {
      const float v = xs[p][swzk1(q + 16 * j, p)];
      ss += v * v;
    }
    ss += __shfl_xor(ss, 1); ss += __shfl_xor(ss, 2);
    ss += __shfl_xor(ss, 4); ss += __shfl_xor(ss, 8);
    if (q == 0) invs[p] = 1.f / fmaxf(sqrtf(ss), EPSN);
  }
  __syncthreads();
  // ---- rescale in LDS + coalesced xn write
  {
    float* xno = xn + ((size_t)n * HWP + pixb) * CC;
    #pragma unroll
    for (int rr = 0; rr < 8; ++rr) {
      const int i = t + rr * 1024;
      const int pp = i >> 7, c = i & 127;      // pp wave-uniform, c lane-varying
      const float v = xs[pp][swzk1(c, pp)] * invs[pp];
      xs[pp][swzk1(c, pp)] = v;
      xno[i] = v;
    }
  }
  __syncthreads();
  // ---- Phase B: dots. wave wv -> k = wv*4..wv*4+3 (wave-uniform w -> s_load);
  // lane = pixel; 32 b128 LDS reads instead of 128 b32.
  {
    const int lane = t & 63;
    const int wv = __builtin_amdgcn_readfirstlane(t >> 6);   // 0..15
    float acc[4] = {0.f, 0.f, 0.f, 0.f};
    #pragma unroll 4
    for (int c4 = 0; c4 < 32; ++c4) {
      const float4 x4 = *(const float4*)&xs[lane][(c4 << 2) ^ ((lane & 31) << 2)];
      #pragma unroll
      for (int kk = 0; kk < 4; ++kk) {
        const float* wr = &w[(wv * 4 + kk) * CC + (c4 << 2)];
        acc[kk] += x4.x * wr[0] + x4.y * wr[1] + x4.z * wr[2] + x4.w * wr[3];
      }
    }
    #pragma unroll
    for (int kk = 0; kk < 4; ++kk) ds[lane][wv * 4 + kk] = acc[kk];
  }
  __syncthreads();
  // ---- Phase C: softmax per pixel. thread (p = t>>4, q = t&15), k = q+16kk
  {
    const int p = t >> 4, q = t & 15;
    float v[4]; float m = -3.4e38f;
    #pragma unroll
    for (int kk = 0; kk < 4; ++kk){ v[kk] = ds[p][q + 16 * kk]; m = fmaxf(m, v[kk]); }
    m = fmaxf(m, __shfl_xor(m, 1)); m = fmaxf(m, __shfl_xor(m, 2));
    m = fmaxf(m, __shfl_xor(m, 4)); m = fmaxf(m, __shfl_xor(m, 8));
    float s = 0.f;
    #pragma unroll
    for (int kk = 0; kk < 4; ++kk){ v[kk] = __expf(v[kk] - m); s += v[kk]; }
    s += __shfl_xor(s, 1); s += __shfl_xor(s, 2);
    s += __shfl_xor(s, 4); s += __shfl_xor(s, 8);
    const float is = 1.f / s;
    #pragma unroll
    for (int kk = 0; kk < 4; ++kk) ds[p][q + 16 * kk] = v[kk] * is;
  }
  __syncthreads();
  {
    float* ao = aout + ((size_t)n * HWP + pixb) * KK_;
    #pragma unroll
    for (int rr = 0; rr < 4; ++rr) {
      const int i = t + rr * 1024;
      ao[i] = ds[i >> 6][i & 63];
    }
  }
}

// =====================================================================
// rank-25 outer-product accumulate. Lane mapping (store-coalescing):
// lane = (h = lane>>5, l5 = lane&31); lane owns k(m) = kbase + 2m + h
// (m = 0..3) and c = l5*4 .. l5*4+3. Wave's 1024 outputs CONTIGUOUS in kc.
// xs read: b128, 32 distinct 16B spans + h-pair broadcast -> conflict-free.
// a read: 2-address broadcast b32 -> conflict-free.
// =====================================================================
__device__ __forceinline__ void dots25(const float (*a_s)[64], const float (*xs)[128],
                                       int kbase, int h, int c0,
                                       float acc[16], float s0[4])
{
  #pragma unroll 5
  for (int p = 0; p < 25; ++p) {
    const float4 x4 = *(const float4*)&xs[p][c0];
    #pragma unroll
    for (int m = 0; m < 4; ++m) {
      const float av = a_s[p][kbase + 2 * m + h];
      s0[m] += av;
      acc[m * 4 + 0] += av * x4.x;
      acc[m * 4 + 1] += av * x4.y;
      acc[m * 4 + 2] += av * x4.z;
      acc[m * 4 + 3] += av * x4.w;
    }
  }
}

// =====================================================================
// Kernel 2: 1296 regional-window blocks (write vlad into T[n][r][kc],
// fully coalesced) + 64 blocks of vlad_full partials. 512 threads (8 waves);
// wave wv owns k = wv*8 .. wv*8+7. launch_bounds caps VGPR at 128.
// =====================================================================
__global__ __launch_bounds__(512, 4) void k2_main(
    const float* __restrict__ xn, const float* __restrict__ aw,
    const float* __restrict__ cent, float* __restrict__ T,
    float* __restrict__ Gpart, float* __restrict__ G0part)
{
  __shared__ __align__(16) float a_s[25][64];
  __shared__ __align__(16) float xs[25][128];
  __shared__ float red[8];
  const int t = threadIdx.x;
  const int lane = t & 63;
  const int wv = t >> 6;            // 0..7
  const int h = lane >> 5;          // 0..1
  const int l5 = lane & 31;
  const int c0 = l5 << 2;
  const int kbase = wv * 8;
  // XCD-chunked bijective swizzle (1360 % 8 == 0): L2 read locality.
  const int bid = (blockIdx.x & 7) * 170 + (blockIdx.x >> 3);

  float acc[16];
  #pragma unroll
  for (int j = 0; j < 16; ++j) acc[j] = 0.f;
  float s0[4];
  #pragma unroll
  for (int m = 0; m < 4; ++m) s0[m] = 0.f;

  if (bid < 1296) {
    // ---------------- regional window ----------------
    const int n = bid / HWO, r = bid % HWO, ho = r / WO, wo = r % WO;
    for (int it = wv; it < 25; it += 8) {
      const int pix = (2 * ho + it / 5) * WW + 2 * wo + (it % 5);
      a_s[it][lane] = aw[((size_t)n * HWP + pix) * KK_ + lane];
      const float* xp = xn + ((size_t)n * HWP + pix) * CC;
      xs[it][lane]      = xp[lane];
      xs[it][lane + 64] = xp[lane + 64];
    }
    __syncthreads();

    dots25(a_s, xs, kbase, h, c0, acc, s0);

    // epilogue: centroid correction, /25, intra-norm (C), global norm (K*C)
    float ssm[4], rnm[4];
    #pragma unroll
    for (int m = 0; m < 4; ++m) {
      const int k = kbase + 2 * m + h;
      const float4 c4 = *(const float4*)&cent[(size_t)k * CC + c0];
      const float cv[4] = {c4.x, c4.y, c4.z, c4.w};
      float ss = 0.f;
      #pragma unroll
      for (int d = 0; d < 4; ++d) {
        const float pv = (acc[m * 4 + d] - cv[d] * s0[m]) * 0.04f;
        acc[m * 4 + d] = pv;
        ss += pv * pv;
      }
      ssm[m] = ss;
    }
    // reduce per-k sumsq over the 32 c-lanes (l5)
    #pragma unroll
    for (int off = 1; off <= 16; off <<= 1) {
      #pragma unroll
      for (int m = 0; m < 4; ++m) ssm[m] += __shfl_xor(ssm[m], off);
    }
    float gpl = 0.f;
    #pragma unroll
    for (int m = 0; m < 4; ++m) {
      rnm[m] = 1.f / fmaxf(sqrtf(ssm[m]), EPSN);
      gpl += ssm[m] * rnm[m] * rnm[m];
    }
    gpl += __shfl_xor(gpl, 32);       // both h-halves -> wave's 8 k's
    if (lane == 0) red[wv] = gpl;
    __syncthreads();
    float gtot = 0.f;
    #pragma unroll
    for (int i = 0; i < 8; ++i) gtot += red[i];
    const float gi = 1.f / fmaxf(sqrtf(gtot), EPSN);

    // fully-coalesced store: 4 x 1KB per wave into T[n][r][kc]
    float* tb = T + ((size_t)n * HWO + r) * KCC + kbase * CC;
    #pragma unroll
    for (int m = 0; m < 4; ++m) {
      const float sc = rnm[m] * gi;
      float4 v;
      v.x = acc[m * 4 + 0] * sc; v.y = acc[m * 4 + 1] * sc;
      v.z = acc[m * 4 + 2] * sc; v.w = acc[m * 4 + 3] * sc;
      *(float4*)&tb[m * 256 + lane * 4] = v;
    }
  } else {
    // ---------------- vlad_full partials: 100-pixel chunk, 4 rounds ------
    const int pid = bid - 1296;            // 0..63
    const int n = pid >> 4, ch = pid & 15;
    const int pixb = n * HWP + ch * 100;   // global pixel index
    #pragma unroll 1
    for (int rr = 0; rr < 4; ++rr) {
      for (int it = wv; it < 25; it += 8) {
        const int pg = pixb + rr * 25 + it;
        a_s[it][lane] = aw[(size_t)pg * KK_ + lane];
        const float* xp = xn + (size_t)pg * CC;
        xs[it][lane]      = xp[lane];
        xs[it][lane + 64] = xp[lane + 64];
      }
      __syncthreads();
      dots25(a_s, xs, kbase, h, c0, acc, s0);
      __syncthreads();
    }
    if (l5 == 0) {
      #pragma unroll
      for (int m = 0; m < 4; ++m)
        G0part[(size_t)pid * KK_ + kbase + 2 * m + h] = s0[m];
    }
    float* gb = Gpart + (size_t)pid * KCC + kbase * CC;
    #pragma unroll
    for (int m = 0; m < 4; ++m) {
      float4 v;
      v.x = acc[m * 4 + 0]; v.y = acc[m * 4 + 1];
      v.z = acc[m * 4 + 2]; v.w = acc[m * 4 + 3];
      *(float4*)&gb[m * 256 + lane * 4] = v;
    }
  }
}

// =====================================================================
// Kernel 4: transpose T[n][r][kc] -> out[n][kc][r]. Coalesced both sides.
// grid = 4n x 128 kc-tiles(64) x 3 r-chunks(112,112,100). 256 threads.
// =====================================================================
__global__ __launch_bounds__(256) void k4_transpose(
    const float* __restrict__ T, float* __restrict__ out)
{
  __shared__ float tile[112][65];
  const int t = threadIdx.x;
  const int b = blockIdx.x;            // 0..1535
  const int n = b / 384;
  const int rem = b % 384;
  const int kcT = rem / 3, rT = rem % 3;
  const int kc0 = kcT * 64;
  const int r0 = rT * 112;
  const int rows = (rT == 2) ? 100 : 112;
  const int w = t >> 6, lane = t & 63;

  for (int rr = w; rr < rows; rr += 4)
    tile[rr][lane] = T[((size_t)n * HWO + r0 + rr) * KCC + kc0 + lane];
  __syncthreads();

  #pragma unroll
  for (int j = 0; j < 16; ++j) {
    const int kcl = w + 4 * j;          // 0..63, wave-uniform
    float* orow = out + (size_t)n * KCC * HWO + (size_t)(kc0 + kcl) * HWO + r0;
    orow[lane] = tile[lane][kcl];
    if (lane + 64 < rows) orow[64 + lane] = tile[64 + lane][kcl];
  }
}

// =====================================================================
// Kernel 3: finalize vlad_full. 4 blocks (one per n) x 1024 threads.
// thread: k = t>>4, 8 c's (c0 = (t&15)*8). Reads 2 MB coalesced.
// =====================================================================
__global__ __launch_bounds__(1024) void k3_full(
    const float* __restrict__ Gpart, const float* __restrict__ G0part,
    const float* __restrict__ cent, float* __restrict__ outF)
{
  __shared__ float red[16];
  const int n = blockIdx.x;
  const int t = threadIdx.x;
  const int k = t >> 4, cg16 = t & 15;
  const int c0 = cg16 * 8;

  float acc[8];
  #pragma unroll
  for (int j = 0; j < 8; ++j) acc[j] = 0.f;
  float g0 = 0.f;
  #pragma unroll 1
  for (int ch = 0; ch < 16; ++ch) {
    const float* gp = Gpart + ((size_t)(n * 16 + ch)) * KCC + (size_t)k * CC + c0;
    const float4 a4 = *(const float4*)(gp);
    const float4 b4 = *(const float4*)(gp + 4);
    acc[0] += a4.x; acc[1] += a4.y; acc[2] += a4.z; acc[3] += a4.w;
    acc[4] += b4.x; acc[5] += b4.y; acc[6] += b4.z; acc[7] += b4.w;
    g0 += G0part[(size_t)(n * 16 + ch) * KK_ + k];
  }

  float ss = 0.f;
  #pragma unroll
  for (int j = 0; j < 8; ++j) {
    const float v = acc[j] - cent[(size_t)k * CC + c0 + j] * g0;
    acc[j] = v;
    ss += v * v;
  }
  ss += __shfl_xor(ss, 1); ss += __shfl_xor(ss, 2);
  ss += __shfl_xor(ss, 4); ss += __shfl_xor(ss, 8);   // over cg16 -> per-k sumsq
  const float rn = 1.f / fmaxf(sqrtf(ss), EPSN);
  float part = (cg16 == 0) ? ss * rn * rn : 0.f;
  #pragma unroll
  for (int o = 1; o < 64; o <<= 1) part += __shfl_xor(part, o);
  if ((t & 63) == 0) red[t >> 6] = part;
  __syncthreads();
  float tot = 0.f;
  #pragma unroll
  for (int i = 0; i < 16; ++i) tot += red[i];
  const float scale = rn * (1.f / fmaxf(sqrtf(tot), EPSN));
  #pragma unroll
  for (int j = 0; j < 8; ++j)
    outF[(size_t)n * KCC + (size_t)k * CC + c0 + j] = acc[j] * scale;
}

// =====================================================================
extern "C" void kernel_launch(void* const* d_in, const int* in_sizes, int n_in,
                              void* d_out, int out_size, void* d_ws, size_t ws_size,
                              hipStream_t stream)
{
  const float* x    = (const float*)d_in[0];
  const float* w    = (const float*)d_in[1];
  const float* cent = (const float*)d_in[2];
  float* out = (float*)d_out;
  float* ws  = (float*)d_ws;

  float* T  = ws + WS_T;
  float* xn = ws + WS_XN;
  float* aw = ws + WS_A;
  float* gp = ws + WS_GP;
  float* g0 = ws + WS_G0;

  k1_norm_assign<<<dim3(100), dim3(1024), 0, stream>>>(x, w, xn, aw);
  k2_main<<<dim3(1360), dim3(512), 0, stream>>>(xn, aw, cent, T, gp, g0);
  k4_transpose<<<dim3(1536), dim3(256), 0, stream>>>(T, out);
  k3_full<<<dim3(NB), dim3(1024), 0, stream>>>(gp, g0, cent,
                                               out + (size_t)NB * KCC * HWO);
}

// Round 7
// 128.848 us; speedup vs baseline: 1.2617x; 1.0460x over previous
//
#include <hip/hip_runtime.h>

#define EPSN 1e-12f

// ---- problem constants ----
#define NB   4
#define CC   128
#define KK_  64
#define HH   40
#define WW   40
#define HWP  1600      // H*W
#define HO   18
#define WO   18
#define HWO  324       // HO*WO
#define KCC  8192      // K*C

// ws layout (floats)
#define WS_T   0                      // 4*324*8192 = 10,616,832
#define WS_XN  10616832               // 4*1600*128 = 819200
#define WS_A   11436032               // 4*1600*64  = 409600
#define WS_GP  11845632               // 64*8192    = 524288
#define WS_G0  12369920               // 64*64      = 4096

// k1 xs swizzle: XOR c-bits[2:6] with px (involution).
static __device__ __forceinline__ int swzk1(int c, int px){ return c ^ ((px & 31) << 2); }

// async global->LDS staging, 16B per lane: dest = ldsbase + lane*16,
// src = per-lane global address (must be 16B aligned).
__device__ __forceinline__ void gl_lds16(const float* g, float* l)
{
  __builtin_amdgcn_global_load_lds(
      (const __attribute__((address_space(1))) void*)g,
      (__attribute__((address_space(3))) void*)l, 16, 0, 0);
}

// =====================================================================
// Kernel 1: per-pixel L2 norm -> xn (pix-major), conv dots + softmax -> a
// grid 100 x 1024 threads. 64 pixels per block. (unchanged from R6)
// =====================================================================
__global__ __launch_bounds__(1024) void k1_norm_assign(
    const float* __restrict__ x, const float* __restrict__ w,
    float* __restrict__ xn, float* __restrict__ aout)
{
  __shared__ __align__(16) float xs[64][128];
  __shared__ float ds[64][65];
  __shared__ float invs[64];
  const int t = threadIdx.x;
  const int b = blockIdx.x;          // 0..99
  const int n = b / 25;
  const int pixb = (b % 25) * 64;
  const float* xb = x + (size_t)n * CC * HWP + pixb;

  // ---- Phase A: coalesced load + swizzled LDS transpose
  {
    const int px = t & 63, cs = t >> 6;   // cs 0..15 (wave-uniform)
    #pragma unroll
    for (int j = 0; j < 8; ++j) {
      const int c = cs + 16 * j;
      xs[px][swzk1(c, px)] = xb[c * HWP + px];
    }
  }
  __syncthreads();
  // ---- per-pixel sumsq -> inv norm
  {
    const int p = t >> 4, q = t & 15;
    float ss = 0.f;
    #pragma unroll
    for (int j = 0; j < 8; ++j) {
      const float v = xs[p][swzk1(q + 16 * j, p)];
      ss += v * v;
    }
    ss += __shfl_xor(ss, 1); ss += __shfl_xor(ss, 2);
    ss += __shfl_xor(ss, 4); ss += __shfl_xor(ss, 8);
    if (q == 0) invs[p] = 1.f / fmaxf(sqrtf(ss), EPSN);
  }
  __syncthreads();
  // ---- rescale in LDS + coalesced xn write
  {
    float* xno = xn + ((size_t)n * HWP + pixb) * CC;
    #pragma unroll
    for (int rr = 0; rr < 8; ++rr) {
      const int i = t + rr * 1024;
      const int pp = i >> 7, c = i & 127;
      const float v = xs[pp][swzk1(c, pp)] * invs[pp];
      xs[pp][swzk1(c, pp)] = v;
      xno[i] = v;
    }
  }
  __syncthreads();
  // ---- Phase B: dots. wave wv -> k = wv*4..wv*4+3 (wave-uniform w -> s_load)
  {
    const int lane = t & 63;
    const int wv = __builtin_amdgcn_readfirstlane(t >> 6);   // 0..15
    float acc[4] = {0.f, 0.f, 0.f, 0.f};
    #pragma unroll 4
    for (int c4 = 0; c4 < 32; ++c4) {
      const float4 x4 = *(const float4*)&xs[lane][(c4 << 2) ^ ((lane & 31) << 2)];
      #pragma unroll
      for (int kk = 0; kk < 4; ++kk) {
        const float* wr = &w[(wv * 4 + kk) * CC + (c4 << 2)];
        acc[kk] += x4.x * wr[0] + x4.y * wr[1] + x4.z * wr[2] + x4.w * wr[3];
      }
    }
    #pragma unroll
    for (int kk = 0; kk < 4; ++kk) ds[lane][wv * 4 + kk] = acc[kk];
  }
  __syncthreads();
  // ---- Phase C: softmax per pixel
  {
    const int p = t >> 4, q = t & 15;
    float v[4]; float m = -3.4e38f;
    #pragma unroll
    for (int kk = 0; kk < 4; ++kk){ v[kk] = ds[p][q + 16 * kk]; m = fmaxf(m, v[kk]); }
    m = fmaxf(m, __shfl_xor(m, 1)); m = fmaxf(m, __shfl_xor(m, 2));
    m = fmaxf(m, __shfl_xor(m, 4)); m = fmaxf(m, __shfl_xor(m, 8));
    float s = 0.f;
    #pragma unroll
    for (int kk = 0; kk < 4; ++kk){ v[kk] = __expf(v[kk] - m); s += v[kk]; }
    s += __shfl_xor(s, 1); s += __shfl_xor(s, 2);
    s += __shfl_xor(s, 4); s += __shfl_xor(s, 8);
    const float is = 1.f / s;
    #pragma unroll
    for (int kk = 0; kk < 4; ++kk) ds[p][q + 16 * kk] = v[kk] * is;
  }
  __syncthreads();
  {
    float* ao = aout + ((size_t)n * HWP + pixb) * KK_;
    #pragma unroll
    for (int rr = 0; rr < 4; ++rr) {
      const int i = t + rr * 1024;
      ao[i] = ds[i >> 6][i & 63];
    }
  }
}

// =====================================================================
// rank-25 outer-product accumulate, both operands b128:
// lane owns k = k0..k0+3 (consecutive, k0 = wv*8 + 4h) and c = c0..c0+3.
// a-read: 2 distinct 16B addrs/wave (broadcast) -> conflict-free.
// x-read: 32 distinct 16B spans, h-dup -> conflict-free.
// =====================================================================
__device__ __forceinline__ void dots25(const float (*a_s)[64], const float (*xs)[128],
                                       int k0, int c0, float acc[16], float s0[4])
{
  #pragma unroll 5
  for (int p = 0; p < 25; ++p) {
    const float4 a4 = *(const float4*)&a_s[p][k0];
    const float4 x4 = *(const float4*)&xs[p][c0];
    const float av[4] = {a4.x, a4.y, a4.z, a4.w};
    #pragma unroll
    for (int m = 0; m < 4; ++m) {
      s0[m] += av[m];
      acc[m * 4 + 0] += av[m] * x4.x;
      acc[m * 4 + 1] += av[m] * x4.y;
      acc[m * 4 + 2] += av[m] * x4.z;
      acc[m * 4 + 3] += av[m] * x4.w;
    }
  }
}

// =====================================================================
// Kernel 2: 1296 regional-window blocks (write vlad into T[n][r][kc],
// fully coalesced) + 64 blocks of vlad_full partials. 512 threads (8 waves);
// wave wv owns k = wv*8 .. wv*8+7. Staging via global_load_lds (16B).
// LDS rows padded (a_s 28, xs 26) to absorb the ragged 16B-call tails;
// over-read global rows stay inside allocated ws.
// =====================================================================
__global__ __launch_bounds__(512, 4) void k2_main(
    const float* __restrict__ xn, const float* __restrict__ aw,
    const float* __restrict__ cent, float* __restrict__ T,
    float* __restrict__ Gpart, float* __restrict__ G0part)
{
  __shared__ __align__(16) float a_s[28][64];
  __shared__ __align__(16) float xs[26][128];
  __shared__ float red[8];
  const int t = threadIdx.x;
  const int lane = t & 63;
  const int wv = t >> 6;            // 0..7
  const int h = lane >> 5;          // 0..1
  const int l5 = lane & 31;
  const int c0 = l5 << 2;
  const int k0 = wv * 8 + h * 4;
  // XCD-chunked bijective swizzle (1360 % 8 == 0): L2 read locality.
  const int bid = (blockIdx.x & 7) * 170 + (blockIdx.x >> 3);

  float acc[16];
  #pragma unroll
  for (int j = 0; j < 16; ++j) acc[j] = 0.f;
  float s0[4];
  #pragma unroll
  for (int m = 0; m < 4; ++m) s0[m] = 0.f;

  if (bid < 1296) {
    // ---------------- regional window ----------------
    const int n = bid / HWO, r = bid % HWO, ho = r / WO, wo = r % WO;
    // a-staging: 7 calls, 4 rows each (rows 0..27)
    if (wv < 7) {
      const int row = 4 * wv + (lane >> 4);
      const int pix = (2 * ho + row / 5) * WW + 2 * wo + row % 5;
      gl_lds16(aw + ((size_t)n * HWP + pix) * KK_ + ((lane & 15) << 2),
               &a_s[4 * wv][0]);
    }
    // x-staging: 13 calls, 2 rows each (rows 0..25)
    {
      const int row = 2 * wv + (lane >> 5);
      const int pix = (2 * ho + row / 5) * WW + 2 * wo + row % 5;
      gl_lds16(xn + ((size_t)n * HWP + pix) * CC + ((lane & 31) << 2),
               &xs[2 * wv][0]);
    }
    if (wv < 5) {
      const int j = wv + 8;
      const int row = 2 * j + (lane >> 5);
      const int pix = (2 * ho + row / 5) * WW + 2 * wo + row % 5;
      gl_lds16(xn + ((size_t)n * HWP + pix) * CC + ((lane & 31) << 2),
               &xs[2 * j][0]);
    }
    __syncthreads();

    dots25(a_s, xs, k0, c0, acc, s0);

    // epilogue: centroid correction, /25, intra-norm (C), global norm (K*C)
    float ssm[4], rnm[4];
    #pragma unroll
    for (int m = 0; m < 4; ++m) {
      const int k = k0 + m;
      const float4 c4 = *(const float4*)&cent[(size_t)k * CC + c0];
      const float cv[4] = {c4.x, c4.y, c4.z, c4.w};
      float ss = 0.f;
      #pragma unroll
      for (int d = 0; d < 4; ++d) {
        const float pv = (acc[m * 4 + d] - cv[d] * s0[m]) * 0.04f;
        acc[m * 4 + d] = pv;
        ss += pv * pv;
      }
      ssm[m] = ss;
    }
    // reduce per-k sumsq over the 32 c-lanes (l5)
    #pragma unroll
    for (int off = 1; off <= 16; off <<= 1) {
      #pragma unroll
      for (int m = 0; m < 4; ++m) ssm[m] += __shfl_xor(ssm[m], off);
    }
    float gpl = 0.f;
    #pragma unroll
    for (int m = 0; m < 4; ++m) {
      rnm[m] = 1.f / fmaxf(sqrtf(ssm[m]), EPSN);
      gpl += ssm[m] * rnm[m] * rnm[m];
    }
    gpl += __shfl_xor(gpl, 32);       // both h-halves -> wave's 8 k's
    if (lane == 0) red[wv] = gpl;
    __syncthreads();
    float gtot = 0.f;
    #pragma unroll
    for (int i = 0; i < 8; ++i) gtot += red[i];
    const float gi = 1.f / fmaxf(sqrtf(gtot), EPSN);

    // fully-coalesced store into T[n][r][kc]
    float* tb = T + ((size_t)n * HWO + r) * KCC;
    #pragma unroll
    for (int m = 0; m < 4; ++m) {
      const float sc = rnm[m] * gi;
      float4 v;
      v.x = acc[m * 4 + 0] * sc; v.y = acc[m * 4 + 1] * sc;
      v.z = acc[m * 4 + 2] * sc; v.w = acc[m * 4 + 3] * sc;
      *(float4*)&tb[(size_t)(k0 + m) * CC + c0] = v;
    }
  } else {
    // ---------------- vlad_full partials: 100-pixel chunk, 4 rounds ------
    const int pid = bid - 1296;            // 0..63
    const int n = pid >> 4, ch = pid & 15;
    #pragma unroll 1
    for (int rr = 0; rr < 4; ++rr) {
      const int pb = n * HWP + ch * 100 + rr * 25;  // global pixel base
      if (wv < 7) {
        const int row = 4 * wv + (lane >> 4);
        gl_lds16(aw + (size_t)(pb + row) * KK_ + ((lane & 15) << 2),
                 &a_s[4 * wv][0]);
      }
      {
        const int row = 2 * wv + (lane >> 5);
        gl_lds16(xn + (size_t)(pb + row) * CC + ((lane & 31) << 2),
                 &xs[2 * wv][0]);
      }
      if (wv < 5) {
        const int j = wv + 8;
        const int row = 2 * j + (lane >> 5);
        gl_lds16(xn + (size_t)(pb + row) * CC + ((lane & 31) << 2),
                 &xs[2 * j][0]);
      }
      __syncthreads();
      dots25(a_s, xs, k0, c0, acc, s0);
      __syncthreads();
    }
    if (l5 == 0) {
      #pragma unroll
      for (int m = 0; m < 4; ++m)
        G0part[(size_t)pid * KK_ + k0 + m] = s0[m];
    }
    float* gb = Gpart + (size_t)pid * KCC;
    #pragma unroll
    for (int m = 0; m < 4; ++m) {
      float4 v;
      v.x = acc[m * 4 + 0]; v.y = acc[m * 4 + 1];
      v.z = acc[m * 4 + 2]; v.w = acc[m * 4 + 3];
      *(float4*)&gb[(size_t)(k0 + m) * CC + c0] = v;
    }
  }
}

// =====================================================================
// Kernel 4: transpose T[n][r][kc] -> out[n][kc][r]. Coalesced both sides.
// =====================================================================
__global__ __launch_bounds__(256) void k4_transpose(
    const float* __restrict__ T, float* __restrict__ out)
{
  __shared__ float tile[112][65];
  const int t = threadIdx.x;
  const int b = blockIdx.x;            // 0..1535
  const int n = b / 384;
  const int rem = b % 384;
  const int kcT = rem / 3, rT = rem % 3;
  const int kc0 = kcT * 64;
  const int r0 = rT * 112;
  const int rows = (rT == 2) ? 100 : 112;
  const int w = t >> 6, lane = t & 63;

  for (int rr = w; rr < rows; rr += 4)
    tile[rr][lane] = T[((size_t)n * HWO + r0 + rr) * KCC + kc0 + lane];
  __syncthreads();

  #pragma unroll
  for (int j = 0; j < 16; ++j) {
    const int kcl = w + 4 * j;          // 0..63, wave-uniform
    float* orow = out + (size_t)n * KCC * HWO + (size_t)(kc0 + kcl) * HWO + r0;
    orow[lane] = tile[lane][kcl];
    if (lane + 64 < rows) orow[64 + lane] = tile[64 + lane][kcl];
  }
}

// =====================================================================
// Kernel 3: finalize vlad_full. 4 blocks (one per n) x 1024 threads.
// =====================================================================
__global__ __launch_bounds__(1024) void k3_full(
    const float* __restrict__ Gpart, const float* __restrict__ G0part,
    const float* __restrict__ cent, float* __restrict__ outF)
{
  __shared__ float red[16];
  const int n = blockIdx.x;
  const int t = threadIdx.x;
  const int k = t >> 4, cg16 = t & 15;
  const int c0 = cg16 * 8;

  float acc[8];
  #pragma unroll
  for (int j = 0; j < 8; ++j) acc[j] = 0.f;
  float g0 = 0.f;
  #pragma unroll 1
  for (int ch = 0; ch < 16; ++ch) {
    const float* gp = Gpart + ((size_t)(n * 16 + ch)) * KCC + (size_t)k * CC + c0;
    const float4 a4 = *(const float4*)(gp);
    const float4 b4 = *(const float4*)(gp + 4);
    acc[0] += a4.x; acc[1] += a4.y; acc[2] += a4.z; acc[3] += a4.w;
    acc[4] += b4.x; acc[5] += b4.y; acc[6] += b4.z; acc[7] += b4.w;
    g0 += G0part[(size_t)(n * 16 + ch) * KK_ + k];
  }

  float ss = 0.f;
  #pragma unroll
  for (int j = 0; j < 8; ++j) {
    const float v = acc[j] - cent[(size_t)k * CC + c0 + j] * g0;
    acc[j] = v;
    ss += v * v;
  }
  ss += __shfl_xor(ss, 1); ss += __shfl_xor(ss, 2);
  ss += __shfl_xor(ss, 4); ss += __shfl_xor(ss, 8);
  const float rn = 1.f / fmaxf(sqrtf(ss), EPSN);
  float part = (cg16 == 0) ? ss * rn * rn : 0.f;
  #pragma unroll
  for (int o = 1; o < 64; o <<= 1) part += __shfl_xor(part, o);
  if ((t & 63) == 0) red[t >> 6] = part;
  __syncthreads();
  float tot = 0.f;
  #pragma unroll
  for (int i = 0; i < 16; ++i) tot += red[i];
  const float scale = rn * (1.f / fmaxf(sqrtf(tot), EPSN));
  #pragma unroll
  for (int j = 0; j < 8; ++j)
    outF[(size_t)n * KCC + (size_t)k * CC + c0 + j] = acc[j] * scale;
}

// =====================================================================
extern "C" void kernel_launch(void* const* d_in, const int* in_sizes, int n_in,
                              void* d_out, int out_size, void* d_ws, size_t ws_size,
                              hipStream_t stream)
{
  const float* x    = (const float*)d_in[0];
  const float* w    = (const float*)d_in[1];
  const float* cent = (const float*)d_in[2];
  float* out = (float*)d_out;
  float* ws  = (float*)d_ws;

  float* T  = ws + WS_T;
  float* xn = ws + WS_XN;
  float* aw = ws + WS_A;
  float* gp = ws + WS_GP;
  float* g0 = ws + WS_G0;

  k1_norm_assign<<<dim3(100), dim3(1024), 0, stream>>>(x, w, xn, aw);
  k2_main<<<dim3(1360), dim3(512), 0, stream>>>(xn, aw, cent, T, gp, g0);
  k4_transpose<<<dim3(1536), dim3(256), 0, stream>>>(T, out);
  k3_full<<<dim3(NB), dim3(1024), 0, stream>>>(gp, g0, cent,
                                               out + (size_t)NB * KCC * HWO);
}